// Round 13
// baseline (52.217 us; speedup 1.0000x reference)
//
#include <hip/hip_runtime.h>
#include <math.h>

// Problem constants
#define BB 16384
#define TT 99
#define RR 10
#define LL 3
#define TILE 33          // 99 = 3*33
#define RPW 16           // rows per wave (4 lanes per row)
#define WPB 4            // waves per block (256 threads, 64 rows/block)

// quad_perm DPP broadcast: every lane of a 4-lane quad gets quad-lane Q's
// value. VALU pipe (~2-4 cy), replaces ds_bpermute (DS pipe, ~120 cy).
#define QPB(v, Q) __int_as_float(__builtin_amdgcn_mov_dpp(                    \
    __float_as_int(v), (Q) * 0x55, 0xF, 0xF, true))

// tanh(x) = 1 - 2/(exp(2x)+1); exact limits at +-inf.
__device__ __forceinline__ float fast_tanh(float x) {
    float e = __expf(2.0f * x);
    return fmaf(-2.0f, __builtin_amdgcn_rcpf(e + 1.0f), 1.0f);
}

// ==================== fused recurrence + epilogue ====================
// 4 lanes per row: slot q owns h-units {q, 4+q} (+ {8+q} for q<2; slots 2,3
// carry a duplicate unit whose result is never read). Full h gathered per
// step with 10 quad_perm DPP ops -- ZERO DS ops on the recurrence chain.
// Tokens+labels pre-classified into one code byte (sel<<2|y) per (row,t).
// Per-tile: coalesced states flush + wave-parallel epilogue (as R12).
// Block = 256 thr = 4 waves, each wave owns 16 rows + its LDS slice -> no
// barriers. Grid 256 blocks = 1024 waves = 4 waves/CU (1/SIMD, structural).
__global__ __launch_bounds__(256, 1)
void rnn_fused_kernel(const int* __restrict__ tok_ids,
                      const float* __restrict__ labels,
                      const float* __restrict__ emb,
                      const float* __restrict__ W,
                      const float* __restrict__ U,
                      const float* __restrict__ bvec,
                      const float* __restrict__ Wo,
                      const float* __restrict__ bo,
                      float* __restrict__ states_out,
                      float* __restrict__ probs_out,
                      float* __restrict__ ws)
{
    __shared__ __align__(16) float          s_st[WPB][RPW * TILE * RR]; // 84,480 B
    __shared__                unsigned char s_code[WPB][RPW * 100];     //  6,400 B

    const int tid = threadIdx.x;
    const int w   = tid >> 6;
    const int l   = tid & 63;
    const int r4  = l >> 2;                   // row within wave (0..15)
    const int q   = l & 3;                    // unit slot (0..3)
    const int rowbase = blockIdx.x * (WPB * RPW) + w * RPW;

    // ---- preamble: classify tokens+labels -> code byte (sel<<2)|y ----
    // covers the wave's 16 rows x 99 steps; all loads coalesced-ish
#pragma unroll 1
    for (int g = 0; g < 5; ++g) {
#pragma unroll
        for (int u = 0; u < 5; ++u) {
            const int p = l + 64 * (g * 5 + u);
            if (p < RPW * TT) {
                const size_t gi = (size_t)rowbase * TT + p;   // contiguous
                const int   tk  = tok_ids[gi];
                const float la1 = labels[gi * LL + 1];
                const float la2 = labels[gi * LL + 2];
                const int   y   = (la1 > 0.5f) ? 1 : ((la2 > 0.5f) ? 2 : 0);
                const int   r   = p / TT;
                s_code[w][r * 100 + (p - r * TT)] = (unsigned char)((tk << 2) | y);
            }
        }
    }

    // ---- per-lane weight columns (lane-varying -> VGPR-resident) ----
    const int uA = q;
    const int uB = 4 + q;
    const int uC = (q < 2) ? 8 + q : q;       // slots 2,3: duplicate (unused)
    float UA[RR], UB[RR], UC[RR];
    float cA1 = bvec[uA], cA2 = cA1;
    float cB1 = bvec[uB], cB2 = cB1;
    float cC1 = bvec[uC], cC2 = cC1;
#pragma unroll
    for (int i = 0; i < RR; ++i) {
        UA[i] = U[i * RR + uA];
        UB[i] = U[i * RR + uB];
        UC[i] = U[i * RR + uC];
        const float wA = W[i * RR + uA];
        const float wB = W[i * RR + uB];
        const float wC = W[i * RR + uC];
        const float e1 = emb[RR + i];         // token-1 row
        const float e2 = emb[2 * RR + i];     // token-2 row
        cA1 = fmaf(e1, wA, cA1); cA2 = fmaf(e2, wA, cA2);
        cB1 = fmaf(e1, wB, cB1); cB2 = fmaf(e2, wB, cB2);
        cC1 = fmaf(e1, wC, cC1); cC2 = fmaf(e2, wC, cC2);
    }

    float hoA = 0.0f, hoB = 0.0f, hoC = 0.0f;
    float loss = 0.0f;
    int   corr = 0;
    int code = (int)s_code[w][r4 * 100];      // prefetch t=0 (quad-uniform bcast)

#pragma unroll 1
    for (int k = 0; k < 3; ++k) {
        // ================== sequential phase: 33 steps ==================
#pragma unroll 1
        for (int tt = 0; tt < TILE; ++tt) {
            const int t   = k * TILE + tt;
            const int cur = code;
            const int tn  = (t + 1 < TT) ? t + 1 : t;
            code = (int)s_code[w][r4 * 100 + tn];     // prefetch next (off-chain)
            const int sel = cur >> 2;

            // gather full h: 10 quad_perm broadcasts (VALU pipe, no LDS)
            float h[RR];
            h[0] = QPB(hoA, 0); h[1] = QPB(hoA, 1);
            h[2] = QPB(hoA, 2); h[3] = QPB(hoA, 3);
            h[4] = QPB(hoB, 0); h[5] = QPB(hoB, 1);
            h[6] = QPB(hoB, 2); h[7] = QPB(hoB, 3);
            h[8] = QPB(hoC, 0); h[9] = QPB(hoC, 1);

            const bool is1 = (sel == 1);
            float aA = is1 ? cA1 : cA2;
            float aB = is1 ? cB1 : cB2;
            float aC = is1 ? cC1 : cC2;
#pragma unroll
            for (int i = 0; i < RR; ++i) {
                aA = fmaf(h[i], UA[i], aA);
                aB = fmaf(h[i], UB[i], aB);
                aC = fmaf(h[i], UC[i], aC);
            }
            const float hnA = fast_tanh(aA);
            const float hnB = fast_tanh(aB);
            const float hnC = fast_tanh(aC);
            if (sel != 0) { hoA = hnA; hoB = hnB; hoC = hnC; }  // Keras masking

            // stage own units (fire-and-forget b32; 2-way banked = free)
            float* sp = &s_st[w][(r4 * TILE + tt) * RR];
            sp[q]     = hoA;
            sp[4 + q] = hoB;
            if (q < 2) sp[8 + q] = hoC;
        }

        // ================== parallel phase (per tile) ==================
        // ---- flush states: 16 rows x 330 floats = 2640 float2, coalesced ----
#pragma unroll
        for (int i = 0; i < 42; ++i) {
            const int p = l + 64 * i;
            if (p < RPW * TILE * RR / 2) {
                const int r = p / 165;
                const int m = p - r * 165;
                const float2 v = *reinterpret_cast<const float2*>(
                    &s_st[w][r * (TILE * RR) + 2 * m]);
                *reinterpret_cast<float2*>(
                    &states_out[(size_t)(rowbase + r) * (TT * RR)
                                + (size_t)k * (TILE * RR) + 2 * m]) = v;
            }
        }

        // ---- fused epilogue: 528 (row,step) pairs, wave-parallel ----
#pragma unroll
        for (int i = 0; i < 9; ++i) {
            const int p = l + 64 * i;
            if (p < RPW * TILE) {
                const int r  = p / TILE;
                const int t2 = p - r * TILE;
                const size_t idx = (size_t)(rowbase + r) * TT + k * TILE + t2;

                const float* hp = &s_st[w][(r * TILE + t2) * RR];
                float l0 = bo[0], l1 = bo[1], l2 = bo[2];
#pragma unroll
                for (int j = 0; j < RR; ++j) {
                    const float hj = hp[j];
                    l0 = fmaf(hj, Wo[j * LL + 0], l0);
                    l1 = fmaf(hj, Wo[j * LL + 1], l1);
                    l2 = fmaf(hj, Wo[j * LL + 2], l2);
                }
                const float e0 = __expf(l0), e1 = __expf(l1), e2 = __expf(l2);
                const float S  = e0 + e1 + e2;
                const float rs = __builtin_amdgcn_rcpf(S);
                probs_out[idx * LL + 0] = e0 * rs;
                probs_out[idx * LL + 1] = e1 * rs;
                probs_out[idx * LL + 2] = e2 * rs;

                const int y = (int)s_code[w][r * 100 + k * TILE + t2] & 3;

                // loss: -log(clip(p_y, 1e-7, 1)) == min(logS - l_y, -log(1e-7))
                const float ly = (y == 0) ? l0 : ((y == 1) ? l1 : l2);
                loss += fminf(__logf(S) - ly, 16.11809565f);

                // accuracy: argmax(logits) == argmax(probs)
                int ap = 0; float pm = l0;
                if (l1 > pm) { ap = 1; pm = l1; }
                if (l2 > pm) { ap = 2; }
                corr += (ap == y) ? 1 : 0;
            }
        }
        // next tile reuses s_st: same-wave DS ordering guarantees safety
    }

    // ---- wave reduction -> one partial per wave (deterministic) ----
    float ls = loss, cs = (float)corr;
#pragma unroll
    for (int off = 32; off > 0; off >>= 1) {
        ls += __shfl_down(ls, off, 64);
        cs += __shfl_down(cs, off, 64);
    }
    if (l == 0) {
        const int wid = blockIdx.x * WPB + w;     // 0..1023
        ws[wid]        = ls;
        ws[1024 + wid] = cs;
    }
}

__global__ __launch_bounds__(256)
void finalize_kernel(const float* __restrict__ ws, float* __restrict__ out_tail)
{
    __shared__ float sl[4], sc[4];
    const int t = threadIdx.x;
    float ls = 0.0f, cs = 0.0f;
#pragma unroll
    for (int i = 0; i < 4; ++i) {
        ls += ws[t + 256 * i];
        cs += ws[1024 + t + 256 * i];
    }
#pragma unroll
    for (int off = 32; off > 0; off >>= 1) {
        ls += __shfl_down(ls, off, 64);
        cs += __shfl_down(cs, off, 64);
    }
    if ((t & 63) == 0) { sl[t >> 6] = ls; sc[t >> 6] = cs; }
    __syncthreads();
    if (t == 0) {
        const float L = sl[0] + sl[1] + sl[2] + sl[3];
        const float C = sc[0] + sc[1] + sc[2] + sc[3];
        const float inv = 1.0f / (float)((size_t)BB * TT);
        out_tail[0] = C * inv;   // accuracy
        out_tail[1] = L * inv;   // loss
    }
}

extern "C" void kernel_launch(void* const* d_in, const int* in_sizes, int n_in,
                              void* d_out, int out_size, void* d_ws, size_t ws_size,
                              hipStream_t stream)
{
    const int*   tok    = (const int*)  d_in[0];
    const float* labels = (const float*)d_in[1];
    // d_in[2] = mask (unused by reference math)
    const float* emb = (const float*)d_in[3];
    const float* W   = (const float*)d_in[4];
    const float* U   = (const float*)d_in[5];
    const float* bv  = (const float*)d_in[6];
    const float* Wo  = (const float*)d_in[7];
    const float* bo  = (const float*)d_in[8];

    float* out    = (float*)d_out;
    float* states = out;                                  // [B,T,10]
    float* probs  = out + (size_t)BB * TT * RR;           // [B,T,3]
    float* tail   = out + (size_t)BB * TT * (RR + LL);    // accuracy, loss
    float* ws     = (float*)d_ws;                         // 2048 floats used

    rnn_fused_kernel<<<BB / (WPB * RPW), 256, 0, stream>>>(
        tok, labels, emb, W, U, bv, Wo, bo, states, probs, ws);
    finalize_kernel<<<1, 256, 0, stream>>>(ws, tail);
}